// Round 10
// baseline (171.750 us; speedup 1.0000x reference)
//
#include <hip/hip_runtime.h>
#include <math.h>

#define BB    16
#define VN    256
#define QN    256
#define VD    512
#define QD    768
#define HK    1536
#define HDIM  512

typedef _Float16 half8 __attribute__((ext_vector_type(8)));
typedef _Float16 half4 __attribute__((ext_vector_type(4)));
typedef float f32x4 __attribute__((ext_vector_type(4)));

// ---------------------------------------------------------------------------
// conv_all: ONE launch for every conversion pre-pass.
// 1D grid, range-decoded:
//   [0,1024)      v rows  -> v16in + vz   (4 rows/block, 1 wave/row)
//   [1024,2048)   q rows  -> q16in + qz
//   [2048,2816)   Wv f32->f16 (float4 chunks)
//   [2816,3968)   Wq f32->f16
//   [3968,3974)   hm -> hs16[0..7] + head-sum row hs16[8]
// ---------------------------------------------------------------------------
__global__ __launch_bounds__(256) void conv_all(
    const float* __restrict__ v, const float* __restrict__ q,
    _Float16* __restrict__ v16in, _Float16* __restrict__ q16in,
    float* __restrict__ vz, float* __restrict__ qz,
    const float* __restrict__ Wv, _Float16* __restrict__ Wv16,
    const float* __restrict__ Wq, _Float16* __restrict__ Wq16,
    const float* __restrict__ hm, _Float16* __restrict__ hs16) {
    int g = blockIdx.x;
    int t = threadIdx.x;
    if (g < 2048) {
        int which = g >> 10;                  // 0: v, 1: q
        int gb = g & 1023;
        const float* src = which ? q : v;
        _Float16* dst = which ? q16in : v16in;
        float* outz = which ? qz : vz;
        int D = which ? QD : VD;
        int w = t >> 6, ln = t & 63;
        int row = gb * 4 + w;
        const float* p = src + (size_t)row * D;
        _Float16* d = dst + (size_t)row * D;
        float s = 0.f;
        for (int c = ln * 4; c < D; c += 256) {
            float4 x = *(const float4*)(p + c);
            s += fabsf(x.x) + fabsf(x.y) + fabsf(x.z) + fabsf(x.w);
            half4 hh = {(_Float16)x.x, (_Float16)x.y, (_Float16)x.z, (_Float16)x.w};
            *(half4*)(d + c) = hh;
        }
        for (int off = 32; off > 0; off >>= 1) s += __shfl_down(s, off);
        if (ln == 0) outz[row] = (s == 0.f) ? 1.f : 0.f;
        return;
    }
    if (g < 3968) {
        int isq = (g >= 2816);
        int gb = isq ? (g - 2816) : (g - 2048);
        const float* src = isq ? Wq : Wv;
        _Float16* dst = isq ? Wq16 : Wv16;
        int n4 = isq ? (HK * QD / 4) : (HK * VD / 4);
        int i = gb * 256 + t;
        if (i < n4) {
            float4 x = ((const float4*)src)[i];
            half4 h = {(_Float16)x.x, (_Float16)x.y, (_Float16)x.z, (_Float16)x.w};
            ((half4*)dst)[i] = h;
        }
        return;
    }
    {
        int k = (g - 3968) * 256 + t;
        if (k >= HK) return;
        float s = 0.f;
#pragma unroll
        for (int h = 0; h < 8; ++h) {
            float x = hm[h * HK + k];
            s += x;
            hs16[h * HK + k] = (_Float16)x;
        }
        hs16[8 * HK + k] = (_Float16)s;
    }
}

// ---------------------------------------------------------------------------
// proj128: m97-class 128x128-tile projection GEMM (f16 inputs), v+q merged.
// 1D grid of 768 with XCD-aware swizzle (W + A panels L2-resident per XCD).
// C16[m,n] = (f16) relu(sum_k A[m,k]*W[n,k] + b[n]); 4 waves, 4x4 acc/wave.
// ---------------------------------------------------------------------------
__global__ __launch_bounds__(256, 2) void proj128(
    const _Float16* __restrict__ v16in, const _Float16* __restrict__ Wv16,
    const float* __restrict__ bv, _Float16* __restrict__ v16,
    const _Float16* __restrict__ q16in, const _Float16* __restrict__ Wq16,
    const float* __restrict__ bq, _Float16* __restrict__ q16) {
    __shared__ _Float16 As[128 * 64];
    __shared__ _Float16 Bs[128 * 64];
    // XCD swizzle: 768 blocks = 8 XCDs x 96; g = xcd*96 + idx
    int lin = blockIdx.x;
    int gg = (lin & 7) * 96 + (lin >> 3);
    int z = gg / 384;
    int r = gg - z * 384;
    int m0 = (r / 12) * 128, n0 = (r % 12) * 128;
    const _Float16* Ain = z ? q16in : v16in;
    const _Float16* W16 = z ? Wq16 : Wv16;
    const float* bias = z ? bq : bv;
    _Float16* C16 = z ? q16 : v16;
    int K = z ? QD : VD;
    int t = threadIdx.x;
    int w = t >> 6, ln = t & 63, quad = ln >> 4, r16 = ln & 15;
    int wi = w & 1, wj = w >> 1;
    int arow = t >> 3, aseg = t & 7;              // 32 rows x 8 segs per pass
    int sg = (aseg ^ (arow & 7)) * 8;
    const _Float16* ApG = Ain + (size_t)(m0 + arow) * K + aseg * 8;
    const _Float16* BpG = W16 + (size_t)(n0 + arow) * K + aseg * 8;
    half8 ra[4], rb[4];
#pragma unroll
    for (int c = 0; c < 4; ++c) {
        ra[c] = *(const half8*)(ApG + (size_t)c * 32 * K);
        rb[c] = *(const half8*)(BpG + (size_t)c * 32 * K);
    }
    f32x4 acc[4][4] = {};
    for (int k0 = 0; k0 < K; k0 += 64) {
        __syncthreads();
#pragma unroll
        for (int c = 0; c < 4; ++c) {
            *(half8*)&As[(c * 32 + arow) * 64 + sg] = ra[c];
            *(half8*)&Bs[(c * 32 + arow) * 64 + sg] = rb[c];
        }
        __syncthreads();
        if (k0 + 64 < K) {
#pragma unroll
            for (int c = 0; c < 4; ++c) {
                ra[c] = *(const half8*)(ApG + (size_t)c * 32 * K + k0 + 64);
                rb[c] = *(const half8*)(BpG + (size_t)c * 32 * K + k0 + 64);
            }
        }
#pragma unroll
        for (int kc = 0; kc < 2; ++kc) {
            half8 af[4], bf[4];
#pragma unroll
            for (int fi = 0; fi < 4; ++fi) {
                int rl = wi * 64 + fi * 16 + r16;
                af[fi] = *(const half8*)&As[rl * 64 + ((kc * 4 + quad) ^ (rl & 7)) * 8];
            }
#pragma unroll
            for (int fj = 0; fj < 4; ++fj) {
                int rl = wj * 64 + fj * 16 + r16;
                bf[fj] = *(const half8*)&Bs[rl * 64 + ((kc * 4 + quad) ^ (rl & 7)) * 8];
            }
#pragma unroll
            for (int fi = 0; fi < 4; ++fi)
#pragma unroll
                for (int fj = 0; fj < 4; ++fj)
                    acc[fi][fj] = __builtin_amdgcn_mfma_f32_16x16x32_f16(
                        af[fi], bf[fj], acc[fi][fj], 0, 0, 0);
        }
    }
#pragma unroll
    for (int fi = 0; fi < 4; ++fi) {
#pragma unroll
        for (int r2 = 0; r2 < 4; ++r2) {
            int m = m0 + wi * 64 + fi * 16 + quad * 4 + r2;
#pragma unroll
            for (int fj = 0; fj < 4; ++fj) {
                int n = n0 + wj * 64 + fj * 16 + r16;
                float x = acc[fi][fj][r2] + bias[n];
                C16[(size_t)m * HK + n] = (_Float16)fmaxf(x, 0.f);
            }
        }
    }
}

// ---------------------------------------------------------------------------
// att_db128: att_db with BK=128 -> HALF the iterations (12) and barriers.
// LDS 72 KB (dbuf A 32K + B 16K + Hl 24K); grid 512 = 2 blocks/CU either way,
// so no occupancy loss (m132's BK=128 penalty doesn't apply here).
// XOR swizzle extended to 16 k-segments: write s^(row&7), read kq^(rl&7).
// Same dbuf + it+2 prefetch + XCD swizzle + epilogue as att_db.
// ---------------------------------------------------------------------------
__global__ __launch_bounds__(256, 2) void att_db128(
    const _Float16* __restrict__ v16, const _Float16* __restrict__ q16,
    const _Float16* __restrict__ hs16, const float* __restrict__ hb,
    const float* __restrict__ vz, const float* __restrict__ qz,
    float* __restrict__ att_out, _Float16* __restrict__ A16) {
    __shared__ _Float16 As[2][64 * 128];   // 32 KB (As[0] reused as Red)
    __shared__ _Float16 Bs[2][32 * 128];   // 16 KB
    __shared__ _Float16 Hl[8 * HK];        // 24 KB
    // bijective XCD swizzle: 512 blocks, lin%8 -> XCD, chunk of 64 = 2 batches
    int lin = blockIdx.x;
    int swz = ((lin & 7) << 6) | (lin >> 3);
    int jb = swz & 7, ib = (swz >> 3) & 3, b = swz >> 5;
    int i0 = ib * 64, j0 = jb * 32;
    int t = threadIdx.x;
    int w = t >> 6, ln = t & 63, quad = ln >> 4, r16 = ln & 15;
    int iw = w & 1, hg = w >> 1, h0 = hg * 4;
    // A staging: row = t>>2 (0..63), 4 chunks at segs (t&3)+4c
    int arow = t >> 2, ascol = t & 3;
    // B staging: row = t>>3 (0..31), 2 chunks at segs (t&7)+8c
    int brow = t >> 3, bscol = t & 7;
    // stage hm rows 0..7 (24 KB), fenced by the first loop barrier
    for (int u = t * 8; u < 8 * HK; u += 256 * 8)
        *(half8*)&Hl[u] = *(const half8*)(hs16 + u);
    const _Float16* ApG = v16 + (size_t)b * VN * HK + (size_t)(i0 + arow) * HK;
    const _Float16* BpG = q16 + (size_t)b * QN * HK + (size_t)(j0 + brow) * HK;
    half8 ra[4], rb[2];
    // prologue: load it=0, stage into buf0, then load it=1
#pragma unroll
    for (int c = 0; c < 4; ++c) ra[c] = *(const half8*)(ApG + (ascol + 4 * c) * 8);
#pragma unroll
    for (int c = 0; c < 2; ++c) rb[c] = *(const half8*)(BpG + (bscol + 8 * c) * 8);
#pragma unroll
    for (int c = 0; c < 4; ++c) {
        int s = ascol + 4 * c;
        *(half8*)&As[0][arow * 128 + (s ^ (arow & 7)) * 8] = ra[c];
    }
#pragma unroll
    for (int c = 0; c < 2; ++c) {
        int s = bscol + 8 * c;
        *(half8*)&Bs[0][brow * 128 + (s ^ (brow & 7)) * 8] = rb[c];
    }
#pragma unroll
    for (int c = 0; c < 4; ++c) ra[c] = *(const half8*)(ApG + 128 + (ascol + 4 * c) * 8);
#pragma unroll
    for (int c = 0; c < 2; ++c) rb[c] = *(const half8*)(BpG + 128 + (bscol + 8 * c) * 8);
    f32x4 acc[4][2][2] = {};
    for (int it = 0; it < 12; ++it) {
        __syncthreads();   // buf[it&1] staged & visible; prior reads of buf[(it+1)&1] done
        int cur = it & 1;
        const _Float16* Ac = As[cur];
        const _Float16* Bc = Bs[cur];
        // stage next tile into the other buffer (regs hold it+1 data)
        if (it + 1 < 12) {
            int nxt = cur ^ 1;
#pragma unroll
            for (int c = 0; c < 4; ++c) {
                int s = ascol + 4 * c;
                *(half8*)&As[nxt][arow * 128 + (s ^ (arow & 7)) * 8] = ra[c];
            }
#pragma unroll
            for (int c = 0; c < 2; ++c) {
                int s = bscol + 8 * c;
                *(half8*)&Bs[nxt][brow * 128 + (s ^ (brow & 7)) * 8] = rb[c];
            }
        }
        // prefetch it+2 from global (load-to-use distance = 1 full iteration)
        if (it + 2 < 12) {
            int kn = (it + 2) * 128;
#pragma unroll
            for (int c = 0; c < 4; ++c)
                ra[c] = *(const half8*)(ApG + kn + (ascol + 4 * c) * 8);
#pragma unroll
            for (int c = 0; c < 2; ++c)
                rb[c] = *(const half8*)(BpG + kn + (bscol + 8 * c) * 8);
        }
        int kb = it * 128;
#pragma unroll
        for (int kc = 0; kc < 4; ++kc) {
            half8 af[2], bf[2];
#pragma unroll
            for (int fi = 0; fi < 2; ++fi) {
                int rl = iw * 32 + fi * 16 + r16;
                af[fi] = *(const half8*)&Ac[rl * 128 + ((kc * 4 + quad) ^ (rl & 7)) * 8];
            }
#pragma unroll
            for (int fj = 0; fj < 2; ++fj) {
                int rl = fj * 16 + r16;
                bf[fj] = *(const half8*)&Bc[rl * 128 + ((kc * 4 + quad) ^ (rl & 7)) * 8];
            }
#pragma unroll
            for (int hh = 0; hh < 4; ++hh) {
                half8 hmv = *(const half8*)&Hl[(h0 + hh) * HK + kb + (kc * 4 + quad) * 8];
#pragma unroll
                for (int fi = 0; fi < 2; ++fi) {
                    half8 am = af[fi] * hmv;
#pragma unroll
                    for (int fj = 0; fj < 2; ++fj)
                        acc[hh][fi][fj] = __builtin_amdgcn_mfma_f32_16x16x32_f16(
                            am, bf[fj], acc[hh][fi][fj], 0, 0, 0);
                }
            }
        }
    }
    // ---- epilogue ----
    float s[2][2][4];
#pragma unroll
    for (int fi = 0; fi < 2; ++fi)
#pragma unroll
        for (int fj = 0; fj < 2; ++fj)
#pragma unroll
            for (int r = 0; r < 4; ++r) {
                float ss = 0.f;
#pragma unroll
                for (int hh = 0; hh < 4; ++hh) ss += acc[hh][fi][fj][r];
                s[fi][fj][r] = ss;
            }
    float hbv[4];
#pragma unroll
    for (int hh = 0; hh < 4; ++hh) hbv[hh] = hb[h0 + hh];
    float hbsum = 0.f;
#pragma unroll
    for (int h = 0; h < 8; ++h) hbsum += hb[h];
    float qm[2];
#pragma unroll
    for (int fj = 0; fj < 2; ++fj) qm[fj] = qz[b * QN + j0 + fj * 16 + r16];
    // own heads -> att_out (fp32, +bias, mask)
    float* outb = att_out + (size_t)b * 8 * VN * QN;
#pragma unroll
    for (int fi = 0; fi < 2; ++fi) {
#pragma unroll
        for (int r = 0; r < 4; ++r) {
            int i = i0 + iw * 32 + fi * 16 + quad * 4 + r;
            float vm = vz[b * VN + i];
#pragma unroll
            for (int fj = 0; fj < 2; ++fj) {
                int j = j0 + fj * 16 + r16;
                bool msk = (vm != 0.f) || (qm[fj] != 0.f);
#pragma unroll
                for (int hh = 0; hh < 4; ++hh) {
                    float x = acc[hh][fi][fj][r] + hbv[hh];
                    if (msk) x = -INFINITY;
                    outb[(size_t)(h0 + hh) * VN * QN + (size_t)i * QN + j] = x;
                }
            }
        }
    }
    // A16 = sum over all 8 heads + sum(hb): exchange hg1 sums via LDS
    __syncthreads();
    float* Red = (float*)&As[0][0];   // [2 iw][32 i][32 j] f32 = 8 KB
    if (hg) {
#pragma unroll
        for (int fi = 0; fi < 2; ++fi)
#pragma unroll
            for (int fj = 0; fj < 2; ++fj)
#pragma unroll
                for (int r = 0; r < 4; ++r)
                    Red[iw * 1024 + (fi * 16 + quad * 4 + r) * 32 + fj * 16 + r16] =
                        s[fi][fj][r];
    }
    __syncthreads();
    if (!hg) {
        _Float16* Ab = A16 + (size_t)b * VN * QN;
#pragma unroll
        for (int fi = 0; fi < 2; ++fi) {
#pragma unroll
            for (int r = 0; r < 4; ++r) {
                int i = i0 + iw * 32 + fi * 16 + quad * 4 + r;
                float vm = vz[b * VN + i];
#pragma unroll
                for (int fj = 0; fj < 2; ++fj) {
                    int j = j0 + fj * 16 + r16;
                    float tot = s[fi][fj][r] +
                                Red[iw * 1024 + (fi * 16 + quad * 4 + r) * 32 + fj * 16 + r16] +
                                hbsum;
                    if (vm != 0.f || qm[fj] != 0.f) tot = -INFINITY;
                    Ab[(size_t)i * QN + j] = (_Float16)tot;
                }
            }
        }
    }
}

// ---------------------------------------------------------------------------
// t_lk_ft: lk[b,k] = sum_i v16[b,i,k] * (sum_j A16[b,i,j] * q16[b,j,k])
// Transpose fused into Bs staging (R9-proven).
// ---------------------------------------------------------------------------
__global__ __launch_bounds__(256) void t_lk_ft(
    const _Float16* __restrict__ A16, const _Float16* __restrict__ q16,
    const _Float16* __restrict__ v16, float* __restrict__ lk) {
    __shared__ _Float16 As[256 * 32];
    __shared__ _Float16 Bs[64 * 32];
    __shared__ float red[16][64];
    int b = blockIdx.y;
    int k0 = blockIdx.x * 64;
    int t = threadIdx.x;
    int w = t >> 6, ln = t & 63, quad = ln >> 4, r16 = ln & 15;
    const _Float16* Ab = A16 + (size_t)b * VN * QN;
    const _Float16* Qb = q16 + (size_t)b * QN * HK;
    int ar = t >> 2, aseg = t & 3;
    int tj = t & 31, tk = t >> 5;     // B-transpose staging coords
    f32x4 acc[4][4] = {};
    for (int j0 = 0; j0 < QN; j0 += 32) {
        half8 a0 = *(const half8*)(Ab + (size_t)(ar +   0) * QN + j0 + aseg * 8);
        half8 a1 = *(const half8*)(Ab + (size_t)(ar +  64) * QN + j0 + aseg * 8);
        half8 a2 = *(const half8*)(Ab + (size_t)(ar + 128) * QN + j0 + aseg * 8);
        half8 a3 = *(const half8*)(Ab + (size_t)(ar + 192) * QN + j0 + aseg * 8);
        half8 q8 = *(const half8*)(Qb + (size_t)(j0 + tj) * HK + k0 + tk * 8);
        __syncthreads();
        *(half8*)&As[(ar +   0) * 32 + aseg * 8] = a0;
        *(half8*)&As[(ar +  64) * 32 + aseg * 8] = a1;
        *(half8*)&As[(ar + 128) * 32 + aseg * 8] = a2;
        *(half8*)&As[(ar + 192) * 32 + aseg * 8] = a3;
#pragma unroll
        for (int e = 0; e < 8; ++e)
            Bs[(tk * 8 + e) * 32 + tj] = q8[e];
        __syncthreads();
        half8 af[4], bf[4];
#pragma unroll
        for (int fi = 0; fi < 4; ++fi)
            af[fi] = *(const half8*)&As[(w * 64 + fi * 16 + r16) * 32 + quad * 8];
#pragma unroll
        for (int fj = 0; fj < 4; ++fj)
            bf[fj] = *(const half8*)&Bs[(fj * 16 + r16) * 32 + quad * 8];
#pragma unroll
        for (int fi = 0; fi < 4; ++fi)
#pragma unroll
            for (int fj = 0; fj < 4; ++fj)
                acc[fi][fj] = __builtin_amdgcn_mfma_f32_16x16x32_f16(
                    af[fi], bf[fj], acc[fi][fj], 0, 0, 0);
    }
    const _Float16* Vb = v16 + (size_t)b * VN * HK;
    float part[4] = {0.f, 0.f, 0.f, 0.f};
#pragma unroll
    for (int fi = 0; fi < 4; ++fi) {
#pragma unroll
        for (int r = 0; r < 4; ++r) {
            int i = w * 64 + fi * 16 + quad * 4 + r;
#pragma unroll
            for (int fj = 0; fj < 4; ++fj) {
                float vv = (float)Vb[(size_t)i * HK + k0 + fj * 16 + r16];
                part[fj] += acc[fi][fj][r] * vv;
            }
        }
    }
#pragma unroll
    for (int fj = 0; fj < 4; ++fj)
        red[w * 4 + quad][fj * 16 + r16] = part[fj];
    __syncthreads();
    if (t < 64) {
        float s = 0.f;
#pragma unroll
        for (int g = 0; g < 16; ++g) s += red[g][t];
        lk[b * HK + k0 + t] = s;
    }
}

// ---------------------------------------------------------------------------
// pool(k=3, sum) + BatchNorm (batch stats, biased var)
// ---------------------------------------------------------------------------
__global__ __launch_bounds__(256) void bn_kernel(
    const float* __restrict__ lk, const float* __restrict__ gamma,
    const float* __restrict__ beta, float* __restrict__ out) {
    int d = blockIdx.x * blockDim.x + threadIdx.x;
    if (d >= HDIM) return;
    float l[BB];
    float mu = 0.f;
#pragma unroll
    for (int b = 0; b < BB; ++b) {
        const float* p = lk + b * HK + 3 * d;
        float s = p[0] + p[1] + p[2];
        l[b] = s;
        mu += s;
    }
    mu *= (1.f / BB);
    float var = 0.f;
#pragma unroll
    for (int b = 0; b < BB; ++b) {
        float dd = l[b] - mu;
        var += dd * dd;
    }
    var *= (1.f / BB);
    float inv = rsqrtf(var + 1e-5f);
    float g = gamma[d], be = beta[d];
#pragma unroll
    for (int b = 0; b < BB; ++b)
        out[b * HDIM + d] = (l[b] - mu) * inv * g + be;
}

// ---------------------------------------------------------------------------
extern "C" void kernel_launch(void* const* d_in, const int* in_sizes, int n_in,
                              void* d_out, int out_size, void* d_ws, size_t ws_size,
                              hipStream_t stream) {
    const float* v  = (const float*)d_in[0];
    const float* q  = (const float*)d_in[1];
    const float* Wv = (const float*)d_in[2];
    const float* bv = (const float*)d_in[3];
    const float* Wq = (const float*)d_in[4];
    const float* bq = (const float*)d_in[5];
    const float* hm = (const float*)d_in[6];
    const float* hb = (const float*)d_in[7];
    const float* gamma = (const float*)d_in[8];
    const float* beta  = (const float*)d_in[9];

    float* out_logits = (float*)d_out;
    float* out_att    = out_logits + BB * HDIM;

    // workspace layout (f16 elements unless noted)
    _Float16* h = (_Float16*)d_ws;
    _Float16* v16   = h;                                   // 16*256*1536
    _Float16* q16   = v16 + (size_t)BB * VN * HK;          // 16*256*1536
    _Float16* A16   = q16 + (size_t)BB * QN * HK;          // 16*256*256
    _Float16* v16in = A16 + (size_t)BB * VN * QN;          // 16*256*512
    _Float16* q16in = v16in + (size_t)BB * VN * VD;        // 16*256*768
    _Float16* Wv16  = q16in + (size_t)BB * QN * QD;        // 1536*512
    _Float16* Wq16  = Wv16 + (size_t)HK * VD;              // 1536*768
    _Float16* hs16  = Wq16 + (size_t)HK * QD;              // 9*1536
    float* lk = (float*)(hs16 + 9 * HK + 8);               // 16*1536 f32
    float* vz = lk + BB * HK;
    float* qz = vz + BB * VN;

    // 1. all conversions + masks in ONE launch
    conv_all<<<dim3(3974), 256, 0, stream>>>(
        v, q, v16in, q16in, vz, qz, Wv, Wv16, Wq, Wq16, hm, hs16);

    // 2. projections -> v16, q16: 128^2 tile, v+q merged, XCD-swizzled grid
    proj128<<<dim3(768), 256, 0, stream>>>(
        v16in, Wv16, bv, v16, q16in, Wq16, bq, q16);

    // 3. att: BK=128 dbuf (12 iters, half the barriers) + XCD swizzle
    att_db128<<<dim3(512), 256, 0, stream>>>(
        v16, q16, hs16, hb, vz, qz, out_att, A16);

    // 4. lk = v16 . (A16 @ q16^T-fused)   (transpose fused into staging)
    t_lk_ft<<<dim3(HK / 64, BB), 256, 0, stream>>>(A16, q16, v16, lk);

    // 5. pool + batchnorm
    bn_kernel<<<dim3((HDIM + 255) / 256), 256, 0, stream>>>(lk, gamma, beta, out_logits);
}

// Round 11
// 171.427 us; speedup vs baseline: 1.0019x; 1.0019x over previous
//
#include <hip/hip_runtime.h>
#include <math.h>

#define BB    16
#define VN    256
#define QN    256
#define VD    512
#define QD    768
#define HK    1536
#define HDIM  512

typedef _Float16 half8 __attribute__((ext_vector_type(8)));
typedef _Float16 half4 __attribute__((ext_vector_type(4)));
typedef float f32x4 __attribute__((ext_vector_type(4)));

// Raw barrier WITHOUT the vmcnt(0) drain __syncthreads carries:
// own LDS ops drained (cross-wave visibility), global loads stay in flight.
__device__ __forceinline__ void lds_barrier() {
    asm volatile("s_waitcnt lgkmcnt(0)" ::: "memory");
    __builtin_amdgcn_s_barrier();
}

// ---------------------------------------------------------------------------
// conv_all: ONE launch for every conversion pre-pass (R8-proven).
// ---------------------------------------------------------------------------
__global__ __launch_bounds__(256) void conv_all(
    const float* __restrict__ v, const float* __restrict__ q,
    _Float16* __restrict__ v16in, _Float16* __restrict__ q16in,
    float* __restrict__ vz, float* __restrict__ qz,
    const float* __restrict__ Wv, _Float16* __restrict__ Wv16,
    const float* __restrict__ Wq, _Float16* __restrict__ Wq16,
    const float* __restrict__ hm, _Float16* __restrict__ hs16) {
    int g = blockIdx.x;
    int t = threadIdx.x;
    if (g < 2048) {
        int which = g >> 10;                  // 0: v, 1: q
        int gb = g & 1023;
        const float* src = which ? q : v;
        _Float16* dst = which ? q16in : v16in;
        float* outz = which ? qz : vz;
        int D = which ? QD : VD;
        int w = t >> 6, ln = t & 63;
        int row = gb * 4 + w;
        const float* p = src + (size_t)row * D;
        _Float16* d = dst + (size_t)row * D;
        float s = 0.f;
        for (int c = ln * 4; c < D; c += 256) {
            float4 x = *(const float4*)(p + c);
            s += fabsf(x.x) + fabsf(x.y) + fabsf(x.z) + fabsf(x.w);
            half4 hh = {(_Float16)x.x, (_Float16)x.y, (_Float16)x.z, (_Float16)x.w};
            *(half4*)(d + c) = hh;
        }
        for (int off = 32; off > 0; off >>= 1) s += __shfl_down(s, off);
        if (ln == 0) outz[row] = (s == 0.f) ? 1.f : 0.f;
        return;
    }
    if (g < 3968) {
        int isq = (g >= 2816);
        int gb = isq ? (g - 2816) : (g - 2048);
        const float* src = isq ? Wq : Wv;
        _Float16* dst = isq ? Wq16 : Wv16;
        int n4 = isq ? (HK * QD / 4) : (HK * VD / 4);
        int i = gb * 256 + t;
        if (i < n4) {
            float4 x = ((const float4*)src)[i];
            half4 h = {(_Float16)x.x, (_Float16)x.y, (_Float16)x.z, (_Float16)x.w};
            ((half4*)dst)[i] = h;
        }
        return;
    }
    {
        int k = (g - 3968) * 256 + t;
        if (k >= HK) return;
        float s = 0.f;
#pragma unroll
        for (int h = 0; h < 8; ++h) {
            float x = hm[h * HK + k];
            s += x;
            hs16[h * HK + k] = (_Float16)x;
        }
        hs16[8 * HK + k] = (_Float16)s;
    }
}

// ---------------------------------------------------------------------------
// proj128: 128x128-tile projection GEMM (f16 inputs), v+q merged, XCD swizzle.
// Raw lds_barrier (no vmcnt drain) -> prefetch loads survive across barriers.
// ---------------------------------------------------------------------------
__global__ __launch_bounds__(256, 2) void proj128(
    const _Float16* __restrict__ v16in, const _Float16* __restrict__ Wv16,
    const float* __restrict__ bv, _Float16* __restrict__ v16,
    const _Float16* __restrict__ q16in, const _Float16* __restrict__ Wq16,
    const float* __restrict__ bq, _Float16* __restrict__ q16) {
    __shared__ _Float16 As[128 * 64];
    __shared__ _Float16 Bs[128 * 64];
    // XCD swizzle: 768 blocks = 8 XCDs x 96; g = xcd*96 + idx
    int lin = blockIdx.x;
    int gg = (lin & 7) * 96 + (lin >> 3);
    int z = gg / 384;
    int r = gg - z * 384;
    int m0 = (r / 12) * 128, n0 = (r % 12) * 128;
    const _Float16* Ain = z ? q16in : v16in;
    const _Float16* W16 = z ? Wq16 : Wv16;
    const float* bias = z ? bq : bv;
    _Float16* C16 = z ? q16 : v16;
    int K = z ? QD : VD;
    int t = threadIdx.x;
    int w = t >> 6, ln = t & 63, quad = ln >> 4, r16 = ln & 15;
    int wi = w & 1, wj = w >> 1;
    int arow = t >> 3, aseg = t & 7;              // 32 rows x 8 segs per pass
    int sg = (aseg ^ (arow & 7)) * 8;
    const _Float16* ApG = Ain + (size_t)(m0 + arow) * K + aseg * 8;
    const _Float16* BpG = W16 + (size_t)(n0 + arow) * K + aseg * 8;
    half8 ra[4], rb[4];
#pragma unroll
    for (int c = 0; c < 4; ++c) {
        ra[c] = *(const half8*)(ApG + (size_t)c * 32 * K);
        rb[c] = *(const half8*)(BpG + (size_t)c * 32 * K);
    }
    f32x4 acc[4][4] = {};
    for (int k0 = 0; k0 < K; k0 += 64) {
        lds_barrier();   // prior reads committed (lgkm) ; vmcnt stays in flight
#pragma unroll
        for (int c = 0; c < 4; ++c) {
            *(half8*)&As[(c * 32 + arow) * 64 + sg] = ra[c];
            *(half8*)&Bs[(c * 32 + arow) * 64 + sg] = rb[c];
        }
        lds_barrier();   // writes visible
        if (k0 + 64 < K) {
#pragma unroll
            for (int c = 0; c < 4; ++c) {
                ra[c] = *(const half8*)(ApG + (size_t)c * 32 * K + k0 + 64);
                rb[c] = *(const half8*)(BpG + (size_t)c * 32 * K + k0 + 64);
            }
        }
#pragma unroll
        for (int kc = 0; kc < 2; ++kc) {
            half8 af[4], bf[4];
#pragma unroll
            for (int fi = 0; fi < 4; ++fi) {
                int rl = wi * 64 + fi * 16 + r16;
                af[fi] = *(const half8*)&As[rl * 64 + ((kc * 4 + quad) ^ (rl & 7)) * 8];
            }
#pragma unroll
            for (int fj = 0; fj < 4; ++fj) {
                int rl = wj * 64 + fj * 16 + r16;
                bf[fj] = *(const half8*)&Bs[rl * 64 + ((kc * 4 + quad) ^ (rl & 7)) * 8];
            }
#pragma unroll
            for (int fi = 0; fi < 4; ++fi)
#pragma unroll
                for (int fj = 0; fj < 4; ++fj)
                    acc[fi][fj] = __builtin_amdgcn_mfma_f32_16x16x32_f16(
                        af[fi], bf[fj], acc[fi][fj], 0, 0, 0);
        }
    }
#pragma unroll
    for (int fi = 0; fi < 4; ++fi) {
#pragma unroll
        for (int r2 = 0; r2 < 4; ++r2) {
            int m = m0 + wi * 64 + fi * 16 + quad * 4 + r2;
#pragma unroll
            for (int fj = 0; fj < 4; ++fj) {
                int n = n0 + wj * 64 + fj * 16 + r16;
                float x = acc[fi][fj][r2] + bias[n];
                C16[(size_t)m * HK + n] = (_Float16)fmaxf(x, 0.f);
            }
        }
    }
}

// ---------------------------------------------------------------------------
// att_db (BK=64, R3/R9 base) with raw lds_barrier in the main loop:
// the it+2 global prefetch now truly stays in flight across barriers
// (no per-iteration vmcnt(0) drain). Everything else unchanged.
// ---------------------------------------------------------------------------
__global__ __launch_bounds__(256, 2) void att_db(
    const _Float16* __restrict__ v16, const _Float16* __restrict__ q16,
    const _Float16* __restrict__ hs16, const float* __restrict__ hb,
    const float* __restrict__ vz, const float* __restrict__ qz,
    float* __restrict__ att_out, _Float16* __restrict__ A16) {
    __shared__ _Float16 As[2][64 * 64];   // 16 KB (As[0] reused as f32 Red in epilogue)
    __shared__ _Float16 Bs[2][32 * 64];   // 8 KB
    __shared__ _Float16 Hl[8 * HK];       // 24 KB
    // bijective XCD swizzle: 512 blocks, lin%8 -> XCD, chunk of 64 = 2 batches
    int lin = blockIdx.x;
    int swz = ((lin & 7) << 6) | (lin >> 3);
    int jb = swz & 7, ib = (swz >> 3) & 3, b = swz >> 5;
    int i0 = ib * 64, j0 = jb * 32;
    int t = threadIdx.x;
    int w = t >> 6, ln = t & 63, quad = ln >> 4, r16 = ln & 15;
    int iw = w & 1, hg = w >> 1, h0 = hg * 4;
    int arow = t >> 3, aseg = t & 7;     // 0..31, 0..7
    int sg = (aseg ^ (arow & 7)) * 8;
    // stage hm rows 0..7 (24 KB), fenced by the first loop barrier
    for (int u = t * 8; u < 8 * HK; u += 256 * 8)
        *(half8*)&Hl[u] = *(const half8*)(hs16 + u);
    const _Float16* ApG = v16 + (size_t)b * VN * HK + (size_t)(i0 + arow) * HK + aseg * 8;
    const _Float16* BpG = q16 + (size_t)b * QN * HK + (size_t)(j0 + arow) * HK + aseg * 8;
    half8 ra[2], rb;
    // prologue: load it=0, stage into buf0, then load it=1
    ra[0] = *(const half8*)(ApG);
    ra[1] = *(const half8*)(ApG + (size_t)32 * HK);
    rb    = *(const half8*)(BpG);
    *(half8*)&As[0][arow * 64 + sg] = ra[0];
    *(half8*)&As[0][(arow + 32) * 64 + sg] = ra[1];
    *(half8*)&Bs[0][arow * 64 + sg] = rb;
    ra[0] = *(const half8*)(ApG + 64);
    ra[1] = *(const half8*)(ApG + (size_t)32 * HK + 64);
    rb    = *(const half8*)(BpG + 64);
    f32x4 acc[4][2][2] = {};
    for (int it = 0; it < 24; ++it) {
        lds_barrier();   // buf[it&1] staged & visible; global prefetch stays in flight
        int cur = it & 1;
        const _Float16* Ac = As[cur];
        const _Float16* Bc = Bs[cur];
        // stage next tile into the other buffer (regs hold it+1 data)
        if (it + 1 < 24) {
            int nxt = cur ^ 1;
            *(half8*)&As[nxt][arow * 64 + sg] = ra[0];
            *(half8*)&As[nxt][(arow + 32) * 64 + sg] = ra[1];
            *(half8*)&Bs[nxt][arow * 64 + sg] = rb;
        }
        // prefetch it+2 from global (stays pending across the next barrier)
        if (it + 2 < 24) {
            int kn = (it + 2) * 64;
            ra[0] = *(const half8*)(ApG + kn);
            ra[1] = *(const half8*)(ApG + (size_t)32 * HK + kn);
            rb    = *(const half8*)(BpG + kn);
        }
        int kb = it * 64;
#pragma unroll
        for (int kc = 0; kc < 2; ++kc) {
            half8 af[2], bf[2];
#pragma unroll
            for (int fi = 0; fi < 2; ++fi) {
                int rl = iw * 32 + fi * 16 + r16;
                af[fi] = *(const half8*)&Ac[rl * 64 + ((kc * 4 + quad) ^ (rl & 7)) * 8];
            }
#pragma unroll
            for (int fj = 0; fj < 2; ++fj) {
                int rl = fj * 16 + r16;
                bf[fj] = *(const half8*)&Bc[rl * 64 + ((kc * 4 + quad) ^ (rl & 7)) * 8];
            }
#pragma unroll
            for (int hh = 0; hh < 4; ++hh) {
                half8 hmv = *(const half8*)&Hl[(h0 + hh) * HK + kb + (kc * 4 + quad) * 8];
#pragma unroll
                for (int fi = 0; fi < 2; ++fi) {
                    half8 am = af[fi] * hmv;
#pragma unroll
                    for (int fj = 0; fj < 2; ++fj)
                        acc[hh][fi][fj] = __builtin_amdgcn_mfma_f32_16x16x32_f16(
                            am, bf[fj], acc[hh][fi][fj], 0, 0, 0);
                }
            }
        }
    }
    // ---- epilogue ----
    float s[2][2][4];
#pragma unroll
    for (int fi = 0; fi < 2; ++fi)
#pragma unroll
        for (int fj = 0; fj < 2; ++fj)
#pragma unroll
            for (int r = 0; r < 4; ++r) {
                float ss = 0.f;
#pragma unroll
                for (int hh = 0; hh < 4; ++hh) ss += acc[hh][fi][fj][r];
                s[fi][fj][r] = ss;
            }
    float hbv[4];
#pragma unroll
    for (int hh = 0; hh < 4; ++hh) hbv[hh] = hb[h0 + hh];
    float hbsum = 0.f;
#pragma unroll
    for (int h = 0; h < 8; ++h) hbsum += hb[h];
    float qm[2];
#pragma unroll
    for (int fj = 0; fj < 2; ++fj) qm[fj] = qz[b * QN + j0 + fj * 16 + r16];
    // own heads -> att_out (fp32, +bias, mask)
    float* outb = att_out + (size_t)b * 8 * VN * QN;
#pragma unroll
    for (int fi = 0; fi < 2; ++fi) {
#pragma unroll
        for (int r = 0; r < 4; ++r) {
            int i = i0 + iw * 32 + fi * 16 + quad * 4 + r;
            float vm = vz[b * VN + i];
#pragma unroll
            for (int fj = 0; fj < 2; ++fj) {
                int j = j0 + fj * 16 + r16;
                bool msk = (vm != 0.f) || (qm[fj] != 0.f);
#pragma unroll
                for (int hh = 0; hh < 4; ++hh) {
                    float x = acc[hh][fi][fj][r] + hbv[hh];
                    if (msk) x = -INFINITY;
                    outb[(size_t)(h0 + hh) * VN * QN + (size_t)i * QN + j] = x;
                }
            }
        }
    }
    // A16 = sum over all 8 heads + sum(hb): exchange hg1 sums via LDS
    __syncthreads();
    float* Red = (float*)&As[0][0];   // [2 iw][32 i][32 j] f32 = 8 KB
    if (hg) {
#pragma unroll
        for (int fi = 0; fi < 2; ++fi)
#pragma unroll
            for (int fj = 0; fj < 2; ++fj)
#pragma unroll
                for (int r = 0; r < 4; ++r)
                    Red[iw * 1024 + (fi * 16 + quad * 4 + r) * 32 + fj * 16 + r16] =
                        s[fi][fj][r];
    }
    __syncthreads();
    if (!hg) {
        _Float16* Ab = A16 + (size_t)b * VN * QN;
#pragma unroll
        for (int fi = 0; fi < 2; ++fi) {
#pragma unroll
            for (int r = 0; r < 4; ++r) {
                int i = i0 + iw * 32 + fi * 16 + quad * 4 + r;
                float vm = vz[b * VN + i];
#pragma unroll
                for (int fj = 0; fj < 2; ++fj) {
                    int j = j0 + fj * 16 + r16;
                    float tot = s[fi][fj][r] +
                                Red[iw * 1024 + (fi * 16 + quad * 4 + r) * 32 + fj * 16 + r16] +
                                hbsum;
                    if (vm != 0.f || qm[fj] != 0.f) tot = -INFINITY;
                    Ab[(size_t)i * QN + j] = (_Float16)tot;
                }
            }
        }
    }
}

// ---------------------------------------------------------------------------
// t_lk_ft: lk[b,k] = sum_i v16[b,i,k] * (sum_j A16[b,i,j] * q16[b,j,k])
// Transpose fused into Bs staging (R9-proven).
// ---------------------------------------------------------------------------
__global__ __launch_bounds__(256) void t_lk_ft(
    const _Float16* __restrict__ A16, const _Float16* __restrict__ q16,
    const _Float16* __restrict__ v16, float* __restrict__ lk) {
    __shared__ _Float16 As[256 * 32];
    __shared__ _Float16 Bs[64 * 32];
    __shared__ float red[16][64];
    int b = blockIdx.y;
    int k0 = blockIdx.x * 64;
    int t = threadIdx.x;
    int w = t >> 6, ln = t & 63, quad = ln >> 4, r16 = ln & 15;
    const _Float16* Ab = A16 + (size_t)b * VN * QN;
    const _Float16* Qb = q16 + (size_t)b * QN * HK;
    int ar = t >> 2, aseg = t & 3;
    int tj = t & 31, tk = t >> 5;     // B-transpose staging coords
    f32x4 acc[4][4] = {};
    for (int j0 = 0; j0 < QN; j0 += 32) {
        half8 a0 = *(const half8*)(Ab + (size_t)(ar +   0) * QN + j0 + aseg * 8);
        half8 a1 = *(const half8*)(Ab + (size_t)(ar +  64) * QN + j0 + aseg * 8);
        half8 a2 = *(const half8*)(Ab + (size_t)(ar + 128) * QN + j0 + aseg * 8);
        half8 a3 = *(const half8*)(Ab + (size_t)(ar + 192) * QN + j0 + aseg * 8);
        half8 q8 = *(const half8*)(Qb + (size_t)(j0 + tj) * HK + k0 + tk * 8);
        __syncthreads();
        *(half8*)&As[(ar +   0) * 32 + aseg * 8] = a0;
        *(half8*)&As[(ar +  64) * 32 + aseg * 8] = a1;
        *(half8*)&As[(ar + 128) * 32 + aseg * 8] = a2;
        *(half8*)&As[(ar + 192) * 32 + aseg * 8] = a3;
#pragma unroll
        for (int e = 0; e < 8; ++e)
            Bs[(tk * 8 + e) * 32 + tj] = q8[e];
        __syncthreads();
        half8 af[4], bf[4];
#pragma unroll
        for (int fi = 0; fi < 4; ++fi)
            af[fi] = *(const half8*)&As[(w * 64 + fi * 16 + r16) * 32 + quad * 8];
#pragma unroll
        for (int fj = 0; fj < 4; ++fj)
            bf[fj] = *(const half8*)&Bs[(fj * 16 + r16) * 32 + quad * 8];
#pragma unroll
        for (int fi = 0; fi < 4; ++fi)
#pragma unroll
            for (int fj = 0; fj < 4; ++fj)
                acc[fi][fj] = __builtin_amdgcn_mfma_f32_16x16x32_f16(
                    af[fi], bf[fj], acc[fi][fj], 0, 0, 0);
    }
    const _Float16* Vb = v16 + (size_t)b * VN * HK;
    float part[4] = {0.f, 0.f, 0.f, 0.f};
#pragma unroll
    for (int fi = 0; fi < 4; ++fi) {
#pragma unroll
        for (int r = 0; r < 4; ++r) {
            int i = w * 64 + fi * 16 + quad * 4 + r;
#pragma unroll
            for (int fj = 0; fj < 4; ++fj) {
                float vv = (float)Vb[(size_t)i * HK + k0 + fj * 16 + r16];
                part[fj] += acc[fi][fj][r] * vv;
            }
        }
    }
#pragma unroll
    for (int fj = 0; fj < 4; ++fj)
        red[w * 4 + quad][fj * 16 + r16] = part[fj];
    __syncthreads();
    if (t < 64) {
        float s = 0.f;
#pragma unroll
        for (int g = 0; g < 16; ++g) s += red[g][t];
        lk[b * HK + k0 + t] = s;
    }
}

// ---------------------------------------------------------------------------
// pool(k=3, sum) + BatchNorm (batch stats, biased var)
// ---------------------------------------------------------------------------
__global__ __launch_bounds__(256) void bn_kernel(
    const float* __restrict__ lk, const float* __restrict__ gamma,
    const float* __restrict__ beta, float* __restrict__ out) {
    int d = blockIdx.x * blockDim.x + threadIdx.x;
    if (d >= HDIM) return;
    float l[BB];
    float mu = 0.f;
#pragma unroll
    for (int b = 0; b < BB; ++b) {
        const float* p = lk + b * HK + 3 * d;
        float s = p[0] + p[1] + p[2];
        l[b] = s;
        mu += s;
    }
    mu *= (1.f / BB);
    float var = 0.f;
#pragma unroll
    for (int b = 0; b < BB; ++b) {
        float dd = l[b] - mu;
        var += dd * dd;
    }
    var *= (1.f / BB);
    float inv = rsqrtf(var + 1e-5f);
    float g = gamma[d], be = beta[d];
#pragma unroll
    for (int b = 0; b < BB; ++b)
        out[b * HDIM + d] = (l[b] - mu) * inv * g + be;
}

// ---------------------------------------------------------------------------
extern "C" void kernel_launch(void* const* d_in, const int* in_sizes, int n_in,
                              void* d_out, int out_size, void* d_ws, size_t ws_size,
                              hipStream_t stream) {
    const float* v  = (const float*)d_in[0];
    const float* q  = (const float*)d_in[1];
    const float* Wv = (const float*)d_in[2];
    const float* bv = (const float*)d_in[3];
    const float* Wq = (const float*)d_in[4];
    const float* bq = (const float*)d_in[5];
    const float* hm = (const float*)d_in[6];
    const float* hb = (const float*)d_in[7];
    const float* gamma = (const float*)d_in[8];
    const float* beta  = (const float*)d_in[9];

    float* out_logits = (float*)d_out;
    float* out_att    = out_logits + BB * HDIM;

    // workspace layout (f16 elements unless noted)
    _Float16* h = (_Float16*)d_ws;
    _Float16* v16   = h;                                   // 16*256*1536
    _Float16* q16   = v16 + (size_t)BB * VN * HK;          // 16*256*1536
    _Float16* A16   = q16 + (size_t)BB * QN * HK;          // 16*256*256
    _Float16* v16in = A16 + (size_t)BB * VN * QN;          // 16*256*512
    _Float16* q16in = v16in + (size_t)BB * VN * VD;        // 16*256*768
    _Float16* Wv16  = q16in + (size_t)BB * QN * QD;        // 1536*512
    _Float16* Wq16  = Wv16 + (size_t)HK * VD;              // 1536*768
    _Float16* hs16  = Wq16 + (size_t)HK * QD;              // 9*1536
    float* lk = (float*)(hs16 + 9 * HK + 8);               // 16*1536 f32
    float* vz = lk + BB * HK;
    float* qz = vz + BB * VN;

    // 1. all conversions + masks in ONE launch
    conv_all<<<dim3(3974), 256, 0, stream>>>(
        v, q, v16in, q16in, vz, qz, Wv, Wv16, Wq, Wq16, hm, hs16);

    // 2. projections -> v16, q16: 128^2 tile, v+q merged, XCD-swizzled grid
    proj128<<<dim3(768), 256, 0, stream>>>(
        v16in, Wv16, bv, v16, q16in, Wq16, bq, q16);

    // 3. att: BK=64 dbuf + raw barriers (prefetch survives across barriers)
    att_db<<<dim3(512), 256, 0, stream>>>(
        v16, q16, hs16, hb, vz, qz, out_att, A16);

    // 4. lk = v16 . (A16 @ q16^T-fused)   (transpose fused into staging)
    t_lk_ft<<<dim3(HK / 64, BB), 256, 0, stream>>>(A16, q16, v16, lk);

    // 5. pool + batchnorm
    bn_kernel<<<dim3((HDIM + 255) / 256), 256, 0, stream>>>(lk, gamma, beta, out_logits);
}

// Round 12
// 169.068 us; speedup vs baseline: 1.0159x; 1.0140x over previous
//
#include <hip/hip_runtime.h>
#include <math.h>

#define BB    16
#define VN    256
#define QN    256
#define VD    512
#define QD    768
#define HK    1536
#define HDIM  512

typedef _Float16 half8 __attribute__((ext_vector_type(8)));
typedef _Float16 half4 __attribute__((ext_vector_type(4)));
typedef float f32x4 __attribute__((ext_vector_type(4)));

// Raw barrier WITHOUT the vmcnt(0) drain __syncthreads carries:
// own LDS ops drained (cross-wave visibility), global loads stay in flight.
__device__ __forceinline__ void lds_barrier() {
    asm volatile("s_waitcnt lgkmcnt(0)" ::: "memory");
    __builtin_amdgcn_s_barrier();
}

// ---------------------------------------------------------------------------
// conv_all: ONE launch for every conversion pre-pass (R8-proven).
// ---------------------------------------------------------------------------
__global__ __launch_bounds__(256) void conv_all(
    const float* __restrict__ v, const float* __restrict__ q,
    _Float16* __restrict__ v16in, _Float16* __restrict__ q16in,
    float* __restrict__ vz, float* __restrict__ qz,
    const float* __restrict__ Wv, _Float16* __restrict__ Wv16,
    const float* __restrict__ Wq, _Float16* __restrict__ Wq16,
    const float* __restrict__ hm, _Float16* __restrict__ hs16) {
    int g = blockIdx.x;
    int t = threadIdx.x;
    if (g < 2048) {
        int which = g >> 10;                  // 0: v, 1: q
        int gb = g & 1023;
        const float* src = which ? q : v;
        _Float16* dst = which ? q16in : v16in;
        float* outz = which ? qz : vz;
        int D = which ? QD : VD;
        int w = t >> 6, ln = t & 63;
        int row = gb * 4 + w;
        const float* p = src + (size_t)row * D;
        _Float16* d = dst + (size_t)row * D;
        float s = 0.f;
        for (int c = ln * 4; c < D; c += 256) {
            float4 x = *(const float4*)(p + c);
            s += fabsf(x.x) + fabsf(x.y) + fabsf(x.z) + fabsf(x.w);
            half4 hh = {(_Float16)x.x, (_Float16)x.y, (_Float16)x.z, (_Float16)x.w};
            *(half4*)(d + c) = hh;
        }
        for (int off = 32; off > 0; off >>= 1) s += __shfl_down(s, off);
        if (ln == 0) outz[row] = (s == 0.f) ? 1.f : 0.f;
        return;
    }
    if (g < 3968) {
        int isq = (g >= 2816);
        int gb = isq ? (g - 2816) : (g - 2048);
        const float* src = isq ? Wq : Wv;
        _Float16* dst = isq ? Wq16 : Wv16;
        int n4 = isq ? (HK * QD / 4) : (HK * VD / 4);
        int i = gb * 256 + t;
        if (i < n4) {
            float4 x = ((const float4*)src)[i];
            half4 h = {(_Float16)x.x, (_Float16)x.y, (_Float16)x.z, (_Float16)x.w};
            ((half4*)dst)[i] = h;
        }
        return;
    }
    {
        int k = (g - 3968) * 256 + t;
        if (k >= HK) return;
        float s = 0.f;
#pragma unroll
        for (int h = 0; h < 8; ++h) {
            float x = hm[h * HK + k];
            s += x;
            hs16[h * HK + k] = (_Float16)x;
        }
        hs16[8 * HK + k] = (_Float16)s;
    }
}

// ---------------------------------------------------------------------------
// proj128: 128x128-tile projection GEMM (f16 inputs), v+q merged, XCD swizzle.
// Raw lds_barrier (no vmcnt drain) -> prefetch loads survive across barriers.
// ---------------------------------------------------------------------------
__global__ __launch_bounds__(256, 2) void proj128(
    const _Float16* __restrict__ v16in, const _Float16* __restrict__ Wv16,
    const float* __restrict__ bv, _Float16* __restrict__ v16,
    const _Float16* __restrict__ q16in, const _Float16* __restrict__ Wq16,
    const float* __restrict__ bq, _Float16* __restrict__ q16) {
    __shared__ _Float16 As[128 * 64];
    __shared__ _Float16 Bs[128 * 64];
    // XCD swizzle: 768 blocks = 8 XCDs x 96; g = xcd*96 + idx
    int lin = blockIdx.x;
    int gg = (lin & 7) * 96 + (lin >> 3);
    int z = gg / 384;
    int r = gg - z * 384;
    int m0 = (r / 12) * 128, n0 = (r % 12) * 128;
    const _Float16* Ain = z ? q16in : v16in;
    const _Float16* W16 = z ? Wq16 : Wv16;
    const float* bias = z ? bq : bv;
    _Float16* C16 = z ? q16 : v16;
    int K = z ? QD : VD;
    int t = threadIdx.x;
    int w = t >> 6, ln = t & 63, quad = ln >> 4, r16 = ln & 15;
    int wi = w & 1, wj = w >> 1;
    int arow = t >> 3, aseg = t & 7;              // 32 rows x 8 segs per pass
    int sg = (aseg ^ (arow & 7)) * 8;
    const _Float16* ApG = Ain + (size_t)(m0 + arow) * K + aseg * 8;
    const _Float16* BpG = W16 + (size_t)(n0 + arow) * K + aseg * 8;
    half8 ra[4], rb[4];
#pragma unroll
    for (int c = 0; c < 4; ++c) {
        ra[c] = *(const half8*)(ApG + (size_t)c * 32 * K);
        rb[c] = *(const half8*)(BpG + (size_t)c * 32 * K);
    }
    f32x4 acc[4][4] = {};
    for (int k0 = 0; k0 < K; k0 += 64) {
        lds_barrier();   // prior reads committed (lgkm) ; vmcnt stays in flight
#pragma unroll
        for (int c = 0; c < 4; ++c) {
            *(half8*)&As[(c * 32 + arow) * 64 + sg] = ra[c];
            *(half8*)&Bs[(c * 32 + arow) * 64 + sg] = rb[c];
        }
        lds_barrier();   // writes visible
        if (k0 + 64 < K) {
#pragma unroll
            for (int c = 0; c < 4; ++c) {
                ra[c] = *(const half8*)(ApG + (size_t)c * 32 * K + k0 + 64);
                rb[c] = *(const half8*)(BpG + (size_t)c * 32 * K + k0 + 64);
            }
        }
#pragma unroll
        for (int kc = 0; kc < 2; ++kc) {
            half8 af[4], bf[4];
#pragma unroll
            for (int fi = 0; fi < 4; ++fi) {
                int rl = wi * 64 + fi * 16 + r16;
                af[fi] = *(const half8*)&As[rl * 64 + ((kc * 4 + quad) ^ (rl & 7)) * 8];
            }
#pragma unroll
            for (int fj = 0; fj < 4; ++fj) {
                int rl = wj * 64 + fj * 16 + r16;
                bf[fj] = *(const half8*)&Bs[rl * 64 + ((kc * 4 + quad) ^ (rl & 7)) * 8];
            }
#pragma unroll
            for (int fi = 0; fi < 4; ++fi)
#pragma unroll
                for (int fj = 0; fj < 4; ++fj)
                    acc[fi][fj] = __builtin_amdgcn_mfma_f32_16x16x32_f16(
                        af[fi], bf[fj], acc[fi][fj], 0, 0, 0);
        }
    }
#pragma unroll
    for (int fi = 0; fi < 4; ++fi) {
#pragma unroll
        for (int r2 = 0; r2 < 4; ++r2) {
            int m = m0 + wi * 64 + fi * 16 + quad * 4 + r2;
#pragma unroll
            for (int fj = 0; fj < 4; ++fj) {
                int n = n0 + wj * 64 + fj * 16 + r16;
                float x = acc[fi][fj][r2] + bias[n];
                C16[(size_t)m * HK + n] = (_Float16)fmaxf(x, 0.f);
            }
        }
    }
}

// ---------------------------------------------------------------------------
// att_2h: 2 heads x 2i x 4j per wave (block 32i x 64j, 4 waves = 4 head
// pairs covering all 8 heads on the SAME tile).
// Mechanism: per kc, 4 am = af*hmv products each feed FOUR independent
// MFMAs (fanout 2->4, pk_mul/MFMA 2->1) -> the read->VALU->MFMA dependency
// chain that throttled att_db's pipes is amortized 2x.
// Same dbuf + it+2 prefetch + lds_barrier + XCD swizzle as att_db.
// A16 head-sum via 3-region epilogue exchange (waves 1-3 -> Red, wave 0 sums).
// ---------------------------------------------------------------------------
__global__ __launch_bounds__(256, 2) void att_2h(
    const _Float16* __restrict__ v16, const _Float16* __restrict__ q16,
    const _Float16* __restrict__ hs16, const float* __restrict__ hb,
    const float* __restrict__ vz, const float* __restrict__ qz,
    float* __restrict__ att_out, _Float16* __restrict__ A16) {
    __shared__ _Float16 As[2][32 * 64];   // 8 KB
    __shared__ _Float16 Bs[2][64 * 64];   // 16 KB
    __shared__ _Float16 Hl[8 * HK];       // 24 KB
    __shared__ float Red[3][32 * 64];     // 24 KB (epilogue head-sum exchange)
    // bijective XCD swizzle: 512 blocks, lin%8 -> XCD, chunk of 64 = 2 batches
    int lin = blockIdx.x;
    int swz = ((lin & 7) << 6) | (lin >> 3);
    int jb = swz & 3, ib = (swz >> 2) & 7, b = swz >> 5;
    int i0 = ib * 32, j0 = jb * 64;
    int t = threadIdx.x;
    int hg = t >> 6, ln = t & 63, quad = ln >> 4, r16 = ln & 15;
    int h0 = hg * 2;
    int arow = t >> 3, aseg = t & 7;     // 0..31, 0..7
    int sg = (aseg ^ (arow & 7)) * 8;
    // stage hm rows 0..7 (24 KB), fenced by the first loop barrier
    for (int u = t * 8; u < 8 * HK; u += 256 * 8)
        *(half8*)&Hl[u] = *(const half8*)(hs16 + u);
    const _Float16* ApG = v16 + (size_t)b * VN * HK + (size_t)(i0 + arow) * HK + aseg * 8;
    const _Float16* BpG = q16 + (size_t)b * QN * HK + (size_t)(j0 + arow) * HK + aseg * 8;
    half8 ra, rb[2];
    // prologue: load it=0, stage into buf0, then load it=1
    ra    = *(const half8*)(ApG);
    rb[0] = *(const half8*)(BpG);
    rb[1] = *(const half8*)(BpG + (size_t)32 * HK);
    *(half8*)&As[0][arow * 64 + sg] = ra;
    *(half8*)&Bs[0][arow * 64 + sg] = rb[0];
    *(half8*)&Bs[0][(arow + 32) * 64 + sg] = rb[1];
    ra    = *(const half8*)(ApG + 64);
    rb[0] = *(const half8*)(BpG + 64);
    rb[1] = *(const half8*)(BpG + (size_t)32 * HK + 64);
    f32x4 acc[2][2][4] = {};
    for (int it = 0; it < 24; ++it) {
        lds_barrier();   // buf[it&1] staged & visible; global prefetch stays in flight
        int cur = it & 1;
        const _Float16* Ac = As[cur];
        const _Float16* Bc = Bs[cur];
        // stage next tile into the other buffer (regs hold it+1 data)
        if (it + 1 < 24) {
            int nxt = cur ^ 1;
            *(half8*)&As[nxt][arow * 64 + sg] = ra;
            *(half8*)&Bs[nxt][arow * 64 + sg] = rb[0];
            *(half8*)&Bs[nxt][(arow + 32) * 64 + sg] = rb[1];
        }
        // prefetch it+2 from global (stays pending across the next barrier)
        if (it + 2 < 24) {
            int kn = (it + 2) * 64;
            ra    = *(const half8*)(ApG + kn);
            rb[0] = *(const half8*)(BpG + kn);
            rb[1] = *(const half8*)(BpG + (size_t)32 * HK + kn);
        }
        int kb = it * 64;
#pragma unroll
        for (int kc = 0; kc < 2; ++kc) {
            half8 af[2], bf[4];
#pragma unroll
            for (int fi = 0; fi < 2; ++fi) {
                int rl = fi * 16 + r16;
                af[fi] = *(const half8*)&Ac[rl * 64 + ((kc * 4 + quad) ^ (rl & 7)) * 8];
            }
#pragma unroll
            for (int fj = 0; fj < 4; ++fj) {
                int rl = fj * 16 + r16;
                bf[fj] = *(const half8*)&Bc[rl * 64 + ((kc * 4 + quad) ^ (rl & 7)) * 8];
            }
#pragma unroll
            for (int hh = 0; hh < 2; ++hh) {
                half8 hmv = *(const half8*)&Hl[(h0 + hh) * HK + kb + (kc * 4 + quad) * 8];
#pragma unroll
                for (int fi = 0; fi < 2; ++fi) {
                    half8 am = af[fi] * hmv;
#pragma unroll
                    for (int fj = 0; fj < 4; ++fj)
                        acc[hh][fi][fj] = __builtin_amdgcn_mfma_f32_16x16x32_f16(
                            am, bf[fj], acc[hh][fi][fj], 0, 0, 0);
                }
            }
        }
    }
    // ---- epilogue ----
    float s[2][4][4];   // fi, fj, r  (sum of this wave's 2 heads)
#pragma unroll
    for (int fi = 0; fi < 2; ++fi)
#pragma unroll
        for (int fj = 0; fj < 4; ++fj)
#pragma unroll
            for (int r = 0; r < 4; ++r)
                s[fi][fj][r] = acc[0][fi][fj][r] + acc[1][fi][fj][r];
    float hbv[2];
#pragma unroll
    for (int hh = 0; hh < 2; ++hh) hbv[hh] = hb[h0 + hh];
    float hbsum = 0.f;
#pragma unroll
    for (int h = 0; h < 8; ++h) hbsum += hb[h];
    float qm[4];
#pragma unroll
    for (int fj = 0; fj < 4; ++fj) qm[fj] = qz[b * QN + j0 + fj * 16 + r16];
    // own heads -> att_out (fp32, +bias, mask)
    float* outb = att_out + (size_t)b * 8 * VN * QN;
#pragma unroll
    for (int fi = 0; fi < 2; ++fi) {
#pragma unroll
        for (int r = 0; r < 4; ++r) {
            int i = i0 + fi * 16 + quad * 4 + r;
            float vm = vz[b * VN + i];
#pragma unroll
            for (int fj = 0; fj < 4; ++fj) {
                int j = j0 + fj * 16 + r16;
                bool msk = (vm != 0.f) || (qm[fj] != 0.f);
#pragma unroll
                for (int hh = 0; hh < 2; ++hh) {
                    float x = acc[hh][fi][fj][r] + hbv[hh];
                    if (msk) x = -INFINITY;
                    outb[(size_t)(h0 + hh) * VN * QN + (size_t)i * QN + j] = x;
                }
            }
        }
    }
    // A16 = sum over all 8 heads + sum(hb): waves 1-3 -> Red, wave 0 sums
    if (hg) {
#pragma unroll
        for (int fi = 0; fi < 2; ++fi)
#pragma unroll
            for (int fj = 0; fj < 4; ++fj)
#pragma unroll
                for (int r = 0; r < 4; ++r)
                    Red[hg - 1][(fi * 16 + quad * 4 + r) * 64 + fj * 16 + r16] =
                        s[fi][fj][r];
    }
    __syncthreads();
    if (!hg) {
        _Float16* Ab = A16 + (size_t)b * VN * QN;
#pragma unroll
        for (int fi = 0; fi < 2; ++fi) {
#pragma unroll
            for (int r = 0; r < 4; ++r) {
                int i = i0 + fi * 16 + quad * 4 + r;
                float vm = vz[b * VN + i];
#pragma unroll
                for (int fj = 0; fj < 4; ++fj) {
                    int j = j0 + fj * 16 + r16;
                    int ri = (fi * 16 + quad * 4 + r) * 64 + fj * 16 + r16;
                    float tot = s[fi][fj][r] + Red[0][ri] + Red[1][ri] + Red[2][ri] + hbsum;
                    if (vm != 0.f || qm[fj] != 0.f) tot = -INFINITY;
                    Ab[(size_t)i * QN + j] = (_Float16)tot;
                }
            }
        }
    }
}

// ---------------------------------------------------------------------------
// t_lk_ft: lk[b,k] = sum_i v16[b,i,k] * (sum_j A16[b,i,j] * q16[b,j,k])
// Transpose fused into Bs staging (R9-proven).
// ---------------------------------------------------------------------------
__global__ __launch_bounds__(256) void t_lk_ft(
    const _Float16* __restrict__ A16, const _Float16* __restrict__ q16,
    const _Float16* __restrict__ v16, float* __restrict__ lk) {
    __shared__ _Float16 As[256 * 32];
    __shared__ _Float16 Bs[64 * 32];
    __shared__ float red[16][64];
    int b = blockIdx.y;
    int k0 = blockIdx.x * 64;
    int t = threadIdx.x;
    int w = t >> 6, ln = t & 63, quad = ln >> 4, r16 = ln & 15;
    const _Float16* Ab = A16 + (size_t)b * VN * QN;
    const _Float16* Qb = q16 + (size_t)b * QN * HK;
    int ar = t >> 2, aseg = t & 3;
    int tj = t & 31, tk = t >> 5;     // B-transpose staging coords
    f32x4 acc[4][4] = {};
    for (int j0 = 0; j0 < QN; j0 += 32) {
        half8 a0 = *(const half8*)(Ab + (size_t)(ar +   0) * QN + j0 + aseg * 8);
        half8 a1 = *(const half8*)(Ab + (size_t)(ar +  64) * QN + j0 + aseg * 8);
        half8 a2 = *(const half8*)(Ab + (size_t)(ar + 128) * QN + j0 + aseg * 8);
        half8 a3 = *(const half8*)(Ab + (size_t)(ar + 192) * QN + j0 + aseg * 8);
        half8 q8 = *(const half8*)(Qb + (size_t)(j0 + tj) * HK + k0 + tk * 8);
        __syncthreads();
        *(half8*)&As[(ar +   0) * 32 + aseg * 8] = a0;
        *(half8*)&As[(ar +  64) * 32 + aseg * 8] = a1;
        *(half8*)&As[(ar + 128) * 32 + aseg * 8] = a2;
        *(half8*)&As[(ar + 192) * 32 + aseg * 8] = a3;
#pragma unroll
        for (int e = 0; e < 8; ++e)
            Bs[(tk * 8 + e) * 32 + tj] = q8[e];
        __syncthreads();
        half8 af[4], bf[4];
#pragma unroll
        for (int fi = 0; fi < 4; ++fi)
            af[fi] = *(const half8*)&As[(w * 64 + fi * 16 + r16) * 32 + quad * 8];
#pragma unroll
        for (int fj = 0; fj < 4; ++fj)
            bf[fj] = *(const half8*)&Bs[(fj * 16 + r16) * 32 + quad * 8];
#pragma unroll
        for (int fi = 0; fi < 4; ++fi)
#pragma unroll
            for (int fj = 0; fj < 4; ++fj)
                acc[fi][fj] = __builtin_amdgcn_mfma_f32_16x16x32_f16(
                    af[fi], bf[fj], acc[fi][fj], 0, 0, 0);
    }
    const _Float16* Vb = v16 + (size_t)b * VN * HK;
    float part[4] = {0.f, 0.f, 0.f, 0.f};
#pragma unroll
    for (int fi = 0; fi < 4; ++fi) {
#pragma unroll
        for (int r = 0; r < 4; ++r) {
            int i = w * 64 + fi * 16 + quad * 4 + r;
#pragma unroll
            for (int fj = 0; fj < 4; ++fj) {
                float vv = (float)Vb[(size_t)i * HK + k0 + fj * 16 + r16];
                part[fj] += acc[fi][fj][r] * vv;
            }
        }
    }
#pragma unroll
    for (int fj = 0; fj < 4; ++fj)
        red[w * 4 + quad][fj * 16 + r16] = part[fj];
    __syncthreads();
    if (t < 64) {
        float s = 0.f;
#pragma unroll
        for (int g = 0; g < 16; ++g) s += red[g][t];
        lk[b * HK + k0 + t] = s;
    }
}

// ---------------------------------------------------------------------------
// pool(k=3, sum) + BatchNorm (batch stats, biased var)
// ---------------------------------------------------------------------------
__global__ __launch_bounds__(256) void bn_kernel(
    const float* __restrict__ lk, const float* __restrict__ gamma,
    const float* __restrict__ beta, float* __restrict__ out) {
    int d = blockIdx.x * blockDim.x + threadIdx.x;
    if (d >= HDIM) return;
    float l[BB];
    float mu = 0.f;
#pragma unroll
    for (int b = 0; b < BB; ++b) {
        const float* p = lk + b * HK + 3 * d;
        float s = p[0] + p[1] + p[2];
        l[b] = s;
        mu += s;
    }
    mu *= (1.f / BB);
    float var = 0.f;
#pragma unroll
    for (int b = 0; b < BB; ++b) {
        float dd = l[b] - mu;
        var += dd * dd;
    }
    var *= (1.f / BB);
    float inv = rsqrtf(var + 1e-5f);
    float g = gamma[d], be = beta[d];
#pragma unroll
    for (int b = 0; b < BB; ++b)
        out[b * HDIM + d] = (l[b] - mu) * inv * g + be;
}

// ---------------------------------------------------------------------------
extern "C" void kernel_launch(void* const* d_in, const int* in_sizes, int n_in,
                              void* d_out, int out_size, void* d_ws, size_t ws_size,
                              hipStream_t stream) {
    const float* v  = (const float*)d_in[0];
    const float* q  = (const float*)d_in[1];
    const float* Wv = (const float*)d_in[2];
    const float* bv = (const float*)d_in[3];
    const float* Wq = (const float*)d_in[4];
    const float* bq = (const float*)d_in[5];
    const float* hm = (const float*)d_in[6];
    const float* hb = (const float*)d_in[7];
    const float* gamma = (const float*)d_in[8];
    const float* beta  = (const float*)d_in[9];

    float* out_logits = (float*)d_out;
    float* out_att    = out_logits + BB * HDIM;

    // workspace layout (f16 elements unless noted)
    _Float16* h = (_Float16*)d_ws;
    _Float16* v16   = h;                                   // 16*256*1536
    _Float16* q16   = v16 + (size_t)BB * VN * HK;          // 16*256*1536
    _Float16* A16   = q16 + (size_t)BB * QN * HK;          // 16*256*256
    _Float16* v16in = A16 + (size_t)BB * VN * QN;          // 16*256*512
    _Float16* q16in = v16in + (size_t)BB * VN * VD;        // 16*256*768
    _Float16* Wv16  = q16in + (size_t)BB * QN * QD;        // 1536*512
    _Float16* Wq16  = Wv16 + (size_t)HK * VD;              // 1536*768
    _Float16* hs16  = Wq16 + (size_t)HK * QD;              // 9*1536
    float* lk = (float*)(hs16 + 9 * HK + 8);               // 16*1536 f32
    float* vz = lk + BB * HK;
    float* qz = vz + BB * VN;

    // 1. all conversions + masks in ONE launch
    conv_all<<<dim3(3974), 256, 0, stream>>>(
        v, q, v16in, q16in, vz, qz, Wv, Wv16, Wq, Wq16, hm, hs16);

    // 2. projections -> v16, q16: 128^2 tile, v+q merged, XCD-swizzled grid
    proj128<<<dim3(768), 256, 0, stream>>>(
        v16in, Wv16, bv, v16, q16in, Wq16, bq, q16);

    // 3. att: 2 heads x 2i x 4j per wave (pk_mul/MFMA halved, fanout doubled)
    att_2h<<<dim3(512), 256, 0, stream>>>(
        v16, q16, hs16, hb, vz, qz, out_att, A16);

    // 4. lk = v16 . (A16 @ q16^T-fused)   (transpose fused into staging)
    t_lk_ft<<<dim3(HK / 64, BB), 256, 0, stream>>>(A16, q16, v16, lk);

    // 5. pool + batchnorm
    bn_kernel<<<dim3((HDIM + 255) / 256), 256, 0, stream>>>(lk, gamma, beta, out_logits);
}